// Round 1
// baseline (2277.661 us; speedup 1.0000x reference)
//
#include <hip/hip_runtime.h>
#include <math.h>

#define B_ 4
#define S_ 2048
#define E_ 1024
#define H_ 16
#define D_ 64
#define M_TOT 8192
#define N_QKV 3072

// ---------------------------------------------------------------------------
// Kernel 1: QKV projection. C = X @ W_qkv + b_qkv, scattered into
// qkv_ws laid out as [3][B][H][S][D] so attention reads are contiguous.
// Classic 64x64 tile, BK=16, 4x4 register blocking, 256 threads.
// ---------------------------------------------------------------------------
__global__ __launch_bounds__(256) void qkv_gemm_k(
    const float* __restrict__ X, const float* __restrict__ W,
    const float* __restrict__ bias, float* __restrict__ qkv) {
  __shared__ float As[64][17];   // +1 pad: read stride 17 breaks bank aliasing
  __shared__ float Bs[16][64];
  const int tid = threadIdx.x;
  const int tx = tid & 15, ty = tid >> 4;
  const int n0 = blockIdx.x * 64;
  const int m0 = blockIdx.y * 64;
  const int arow = tid >> 2, acol = (tid & 3) * 4;
  const int brow = tid >> 4, bcol = (tid & 15) * 4;
  float acc[4][4] = {};
  for (int k0 = 0; k0 < E_; k0 += 16) {
    float4 av = *reinterpret_cast<const float4*>(&X[(size_t)(m0 + arow) * E_ + k0 + acol]);
    *reinterpret_cast<float4*>(&Bs[brow][bcol]) =
        *reinterpret_cast<const float4*>(&W[(size_t)(k0 + brow) * N_QKV + n0 + bcol]);
    As[arow][acol + 0] = av.x; As[arow][acol + 1] = av.y;
    As[arow][acol + 2] = av.z; As[arow][acol + 3] = av.w;
    __syncthreads();
#pragma unroll
    for (int kk = 0; kk < 16; ++kk) {
      float a0 = As[ty * 4 + 0][kk], a1 = As[ty * 4 + 1][kk];
      float a2 = As[ty * 4 + 2][kk], a3 = As[ty * 4 + 3][kk];
      float4 bv = *reinterpret_cast<const float4*>(&Bs[kk][tx * 4]);
      acc[0][0] += a0 * bv.x; acc[0][1] += a0 * bv.y; acc[0][2] += a0 * bv.z; acc[0][3] += a0 * bv.w;
      acc[1][0] += a1 * bv.x; acc[1][1] += a1 * bv.y; acc[1][2] += a1 * bv.z; acc[1][3] += a1 * bv.w;
      acc[2][0] += a2 * bv.x; acc[2][1] += a2 * bv.y; acc[2][2] += a2 * bv.z; acc[2][3] += a2 * bv.w;
      acc[3][0] += a3 * bv.x; acc[3][1] += a3 * bv.y; acc[3][2] += a3 * bv.z; acc[3][3] += a3 * bv.w;
    }
    __syncthreads();
  }
  // epilogue: bias + scatter. n0 is 64-aligned so (which, h) constant per block.
  const int which = n0 >> 10;
  const int h = (n0 & 1023) >> 6;
  float bl[4];
#pragma unroll
  for (int j = 0; j < 4; ++j) bl[j] = bias[n0 + tx * 4 + j];
#pragma unroll
  for (int i = 0; i < 4; ++i) {
    int m = m0 + ty * 4 + i;
    int bi = m >> 11, si = m & 2047;
    float4 v = make_float4(acc[i][0] + bl[0], acc[i][1] + bl[1],
                           acc[i][2] + bl[2], acc[i][3] + bl[3]);
    *reinterpret_cast<float4*>(
        &qkv[((((size_t)which * B_ + bi) * H_ + h) * S_ + si) * D_ + tx * 4]) = v;
  }
}

// ---------------------------------------------------------------------------
// Kernel 2: flash attention (fp32). One block = one (b,h) x 64-query tile.
// Iterates 32-key steps with online softmax; O accumulator in registers.
// ---------------------------------------------------------------------------
__global__ __launch_bounds__(256) void attn_k(const float* __restrict__ qkv,
                                              float* __restrict__ ctx) {
  __shared__ float Qs[64][65];
  __shared__ float Ks[32][65];
  __shared__ float Vs[32][64];
  __shared__ float Ss[64][33];
  __shared__ float alphas[64];
  __shared__ float lbuf[64];
  const int tid = threadIdx.x;
  const int tx = tid & 15, ty = tid >> 4;
  const int q0 = blockIdx.x * 64;
  const int bh = blockIdx.y;
  const int b = bh >> 4, h = bh & 15;
  const size_t plane = ((size_t)b * H_ + h) * (size_t)S_ * D_;
  const size_t sz = (size_t)B_ * H_ * S_ * D_;
  const float* Qp = qkv + plane;
  const float* Kp = qkv + sz + plane;
  const float* Vp = qkv + 2 * sz + plane;

  {
    int row = tid >> 4, col = (tid & 15) * 4;
#pragma unroll
    for (int it = 0; it < 4; ++it) {
      float4 v = *reinterpret_cast<const float4*>(&Qp[(size_t)(q0 + row + it * 16) * D_ + col]);
      Qs[row + it * 16][col + 0] = v.x; Qs[row + it * 16][col + 1] = v.y;
      Qs[row + it * 16][col + 2] = v.z; Qs[row + it * 16][col + 3] = v.w;
    }
  }
  float O[4][4] = {};
  float m_r = -1e30f, l_r = 0.f;

  for (int k0 = 0; k0 < S_; k0 += 32) {
    __syncthreads();  // prev iteration done reading Ks/Vs/Ss (also covers Q load)
    {
      int row = tid >> 4, col = (tid & 15) * 4;
#pragma unroll
      for (int it = 0; it < 2; ++it) {
        float4 kv = *reinterpret_cast<const float4*>(&Kp[(size_t)(k0 + row + it * 16) * D_ + col]);
        Ks[row + it * 16][col + 0] = kv.x; Ks[row + it * 16][col + 1] = kv.y;
        Ks[row + it * 16][col + 2] = kv.z; Ks[row + it * 16][col + 3] = kv.w;
        *reinterpret_cast<float4*>(&Vs[row + it * 16][col]) =
            *reinterpret_cast<const float4*>(&Vp[(size_t)(k0 + row + it * 16) * D_ + col]);
      }
    }
    __syncthreads();
    // scores tile: rows ty*4+i, cols tx*2+j
    {
      float s[4][2] = {};
      for (int d = 0; d < 64; ++d) {
        float kv0 = Ks[tx * 2 + 0][d], kv1 = Ks[tx * 2 + 1][d];
#pragma unroll
        for (int i = 0; i < 4; ++i) {
          float qv = Qs[ty * 4 + i][d];
          s[i][0] += qv * kv0;
          s[i][1] += qv * kv1;
        }
      }
#pragma unroll
      for (int i = 0; i < 4; ++i) {
        Ss[ty * 4 + i][tx * 2 + 0] = s[i][0] * 0.125f;
        Ss[ty * 4 + i][tx * 2 + 1] = s[i][1] * 0.125f;
      }
    }
    __syncthreads();
    // online-softmax row pass (threads 0..63 own one row each)
    if (tid < 64) {
      float rm = -1e30f;
#pragma unroll
      for (int c = 0; c < 32; ++c) rm = fmaxf(rm, Ss[tid][c]);
      float newm = fmaxf(m_r, rm);
      float alpha = __expf(m_r - newm);
      float sum = 0.f;
#pragma unroll
      for (int c = 0; c < 32; ++c) {
        float p = __expf(Ss[tid][c] - newm);
        Ss[tid][c] = p;
        sum += p;
      }
      l_r = l_r * alpha + sum;
      m_r = newm;
      alphas[tid] = alpha;
    }
    __syncthreads();
    // O = O*alpha + P @ V
    {
      float al[4];
#pragma unroll
      for (int i = 0; i < 4; ++i) al[i] = alphas[ty * 4 + i];
#pragma unroll
      for (int i = 0; i < 4; ++i)
#pragma unroll
        for (int j = 0; j < 4; ++j) O[i][j] *= al[i];
      for (int kk = 0; kk < 32; ++kk) {
        float4 vv = *reinterpret_cast<const float4*>(&Vs[kk][tx * 4]);
#pragma unroll
        for (int i = 0; i < 4; ++i) {
          float p = Ss[ty * 4 + i][kk];
          O[i][0] += p * vv.x; O[i][1] += p * vv.y;
          O[i][2] += p * vv.z; O[i][3] += p * vv.w;
        }
      }
    }
  }
  if (tid < 64) lbuf[tid] = l_r;
  __syncthreads();
  // write ctx in [B][S][E] layout so the output GEMM is a plain GEMM
#pragma unroll
  for (int i = 0; i < 4; ++i) {
    float inv = 1.f / lbuf[ty * 4 + i];
    float4 v = make_float4(O[i][0] * inv, O[i][1] * inv, O[i][2] * inv, O[i][3] * inv);
    *reinterpret_cast<float4*>(
        &ctx[((size_t)b * S_ + q0 + ty * 4 + i) * E_ + h * D_ + tx * 4]) = v;
  }
}

// ---------------------------------------------------------------------------
// Kernel 3: output projection. out = ctx @ W_out + b_out.
// ---------------------------------------------------------------------------
__global__ __launch_bounds__(256) void out_gemm_k(
    const float* __restrict__ Cx, const float* __restrict__ W,
    const float* __restrict__ bias, float* __restrict__ out) {
  __shared__ float As[64][17];
  __shared__ float Bs[16][64];
  const int tid = threadIdx.x;
  const int tx = tid & 15, ty = tid >> 4;
  const int n0 = blockIdx.x * 64;
  const int m0 = blockIdx.y * 64;
  const int arow = tid >> 2, acol = (tid & 3) * 4;
  const int brow = tid >> 4, bcol = (tid & 15) * 4;
  float acc[4][4] = {};
  for (int k0 = 0; k0 < E_; k0 += 16) {
    float4 av = *reinterpret_cast<const float4*>(&Cx[(size_t)(m0 + arow) * E_ + k0 + acol]);
    *reinterpret_cast<float4*>(&Bs[brow][bcol]) =
        *reinterpret_cast<const float4*>(&W[(size_t)(k0 + brow) * E_ + n0 + bcol]);
    As[arow][acol + 0] = av.x; As[arow][acol + 1] = av.y;
    As[arow][acol + 2] = av.z; As[arow][acol + 3] = av.w;
    __syncthreads();
#pragma unroll
    for (int kk = 0; kk < 16; ++kk) {
      float a0 = As[ty * 4 + 0][kk], a1 = As[ty * 4 + 1][kk];
      float a2 = As[ty * 4 + 2][kk], a3 = As[ty * 4 + 3][kk];
      float4 bv = *reinterpret_cast<const float4*>(&Bs[kk][tx * 4]);
      acc[0][0] += a0 * bv.x; acc[0][1] += a0 * bv.y; acc[0][2] += a0 * bv.z; acc[0][3] += a0 * bv.w;
      acc[1][0] += a1 * bv.x; acc[1][1] += a1 * bv.y; acc[1][2] += a1 * bv.z; acc[1][3] += a1 * bv.w;
      acc[2][0] += a2 * bv.x; acc[2][1] += a2 * bv.y; acc[2][2] += a2 * bv.z; acc[2][3] += a2 * bv.w;
      acc[3][0] += a3 * bv.x; acc[3][1] += a3 * bv.y; acc[3][2] += a3 * bv.z; acc[3][3] += a3 * bv.w;
    }
    __syncthreads();
  }
  float bl[4];
#pragma unroll
  for (int j = 0; j < 4; ++j) bl[j] = bias[n0 + tx * 4 + j];
#pragma unroll
  for (int i = 0; i < 4; ++i) {
    int m = m0 + ty * 4 + i;
    float4 v = make_float4(acc[i][0] + bl[0], acc[i][1] + bl[1],
                           acc[i][2] + bl[2], acc[i][3] + bl[3]);
    *reinterpret_cast<float4*>(&out[(size_t)m * E_ + n0 + tx * 4]) = v;
  }
}

extern "C" void kernel_launch(void* const* d_in, const int* in_sizes, int n_in,
                              void* d_out, int out_size, void* d_ws, size_t ws_size,
                              hipStream_t stream) {
  const float* x    = (const float*)d_in[0];
  const float* Wqkv = (const float*)d_in[1];
  const float* bqkv = (const float*)d_in[2];
  const float* Wout = (const float*)d_in[3];
  const float* bout = (const float*)d_in[4];
  float* out = (float*)d_out;

  float* qkv_ws = (float*)d_ws;                               // 3*B*H*S*D floats = 100.7 MB
  float* ctx_ws = qkv_ws + (size_t)3 * B_ * H_ * S_ * D_;     // + B*S*E floats   =  33.6 MB

  qkv_gemm_k<<<dim3(N_QKV / 64, M_TOT / 64), 256, 0, stream>>>(x, Wqkv, bqkv, qkv_ws);
  attn_k<<<dim3(S_ / 64, B_ * H_), 256, 0, stream>>>(qkv_ws, ctx_ws);
  out_gemm_k<<<dim3(E_ / 64, M_TOT / 64), 256, 0, stream>>>(ctx_ws, Wout, bout, out);
}

// Round 2
// 1104.595 us; speedup vs baseline: 2.0620x; 2.0620x over previous
//
#include <hip/hip_runtime.h>
#include <math.h>

#define B_ 4
#define S_ 2048
#define E_ 1024
#define H_ 16
#define D_ 64
#define M_TOT 8192
#define N_QKV 3072

typedef __attribute__((ext_vector_type(8))) __bf16 bf16x8;
typedef __attribute__((ext_vector_type(8))) unsigned short u16x8;
typedef __attribute__((ext_vector_type(16))) float f32x16;

static __device__ __forceinline__ unsigned short f2bf(float f) {
  union { float f; unsigned int u; } x; x.f = f;
  unsigned int r = x.u + 0x7FFFu + ((x.u >> 16) & 1u);
  return (unsigned short)(r >> 16);
}
static __device__ __forceinline__ float bf2f(unsigned short u) {
  union { unsigned int u; float f; } x; x.u = ((unsigned int)u) << 16;
  return x.f;
}

// ---------------------------------------------------------------------------
// Kernel 1: QKV projection (fp32 compute), OUTPUT STORED AS BF16 into
// qkv_ws laid out [3][B][H][S][D] so attention reads are contiguous bf16.
// ---------------------------------------------------------------------------
__global__ __launch_bounds__(256) void qkv_gemm_k(
    const float* __restrict__ X, const float* __restrict__ W,
    const float* __restrict__ bias, unsigned short* __restrict__ qkv) {
  __shared__ float As[64][17];
  __shared__ float Bs[16][64];
  const int tid = threadIdx.x;
  const int tx = tid & 15, ty = tid >> 4;
  const int n0 = blockIdx.x * 64;
  const int m0 = blockIdx.y * 64;
  const int arow = tid >> 2, acol = (tid & 3) * 4;
  const int brow = tid >> 4, bcol = (tid & 15) * 4;
  float acc[4][4] = {};
  for (int k0 = 0; k0 < E_; k0 += 16) {
    float4 av = *reinterpret_cast<const float4*>(&X[(size_t)(m0 + arow) * E_ + k0 + acol]);
    *reinterpret_cast<float4*>(&Bs[brow][bcol]) =
        *reinterpret_cast<const float4*>(&W[(size_t)(k0 + brow) * N_QKV + n0 + bcol]);
    As[arow][acol + 0] = av.x; As[arow][acol + 1] = av.y;
    As[arow][acol + 2] = av.z; As[arow][acol + 3] = av.w;
    __syncthreads();
#pragma unroll
    for (int kk = 0; kk < 16; ++kk) {
      float a0 = As[ty * 4 + 0][kk], a1 = As[ty * 4 + 1][kk];
      float a2 = As[ty * 4 + 2][kk], a3 = As[ty * 4 + 3][kk];
      float4 bv = *reinterpret_cast<const float4*>(&Bs[kk][tx * 4]);
      acc[0][0] += a0 * bv.x; acc[0][1] += a0 * bv.y; acc[0][2] += a0 * bv.z; acc[0][3] += a0 * bv.w;
      acc[1][0] += a1 * bv.x; acc[1][1] += a1 * bv.y; acc[1][2] += a1 * bv.z; acc[1][3] += a1 * bv.w;
      acc[2][0] += a2 * bv.x; acc[2][1] += a2 * bv.y; acc[2][2] += a2 * bv.z; acc[2][3] += a2 * bv.w;
      acc[3][0] += a3 * bv.x; acc[3][1] += a3 * bv.y; acc[3][2] += a3 * bv.z; acc[3][3] += a3 * bv.w;
    }
    __syncthreads();
  }
  const int which = n0 >> 10;
  const int h = (n0 & 1023) >> 6;
  float bl[4];
#pragma unroll
  for (int j = 0; j < 4; ++j) bl[j] = bias[n0 + tx * 4 + j];
#pragma unroll
  for (int i = 0; i < 4; ++i) {
    int mr = m0 + ty * 4 + i;
    int bi = mr >> 11, si = mr & 2047;
    ushort4 v;
    v.x = f2bf(acc[i][0] + bl[0]); v.y = f2bf(acc[i][1] + bl[1]);
    v.z = f2bf(acc[i][2] + bl[2]); v.w = f2bf(acc[i][3] + bl[3]);
    *reinterpret_cast<ushort4*>(
        &qkv[((((size_t)which * B_ + bi) * H_ + h) * S_ + si) * D_ + tx * 4]) = v;
  }
}

// ---------------------------------------------------------------------------
// Kernel 2: bf16 MFMA flash attention, swapped QK^T (mfma(K, Q^T) -> S^T).
// Block = 256 thr (4 waves), QBLK=128 (32 q-rows/wave), KVBLK=32, NSTEP=64.
// LDS: K tile [32][64] bf16 + V^T tile [64][32] bf16, XOR-swizzled
// (byte ^= (row&7)<<4), double-buffered (16 KiB). Softmax fully in-register:
// lane holds 16 of 32 key-scores for one q-row (col = lane&31), the other 16
// live in lane^32 -> one shfl_xor(32) completes row reductions.
// ---------------------------------------------------------------------------
__global__ __launch_bounds__(256, 4) void attn_k(
    const unsigned short* __restrict__ qkv, float* __restrict__ ctx) {
  __shared__ unsigned short lds[2][4096];  // per buf: 4096B K + 4096B Vt
  const int tid = threadIdx.x;
  const int wv = tid >> 6;
  const int lane = tid & 63;
  const int ln = lane & 31;
  const int hh = lane >> 5;
  const int q0 = blockIdx.x * 128;
  const int bh = blockIdx.y;
  const int b = bh >> 4, head = bh & 15;
  const size_t SZ = (size_t)B_ * H_ * S_ * D_;
  const size_t plane = ((size_t)b * H_ + head) * (size_t)S_ * D_;
  const unsigned short* Qp = qkv + plane;
  const unsigned short* Kp = qkv + SZ + plane;
  const unsigned short* Vp = qkv + 2 * SZ + plane;

  // Q fragments in registers, pre-scaled by (1/8)*log2(e)
  const float SC = 0.125f * 1.4426950408889634f;
  const int qrow = q0 + wv * 32 + ln;
  bf16x8 qf[4];
#pragma unroll
  for (int db = 0; db < 4; ++db) {
    u16x8 qr = *reinterpret_cast<const u16x8*>(Qp + (size_t)qrow * D_ + db * 16 + hh * 8);
    u16x8 qs;
#pragma unroll
    for (int j = 0; j < 8; ++j) qs[j] = f2bf(bf2f(qr[j]) * SC);
    qf[db] = __builtin_bit_cast(bf16x8, qs);
  }

  // staging roles (per thread)
  const int krow = tid >> 3, kg = tid & 7;
  const int vk = tid & 31, vd0 = (tid >> 5) * 8;
  const int kwoff = (krow * 128 + kg * 16) ^ ((krow & 7) << 4);
  char* lbA = (char*)&lds[0][0];
  char* lbB = (char*)&lds[1][0];

  // prologue: stage K/V tile 0 into buffer A
  {
    u16x8 kr = *reinterpret_cast<const u16x8*>(Kp + (size_t)krow * D_ + kg * 8);
    u16x8 vr = *reinterpret_cast<const u16x8*>(Vp + (size_t)vk * D_ + vd0);
    *reinterpret_cast<u16x8*>(lbA + kwoff) = kr;
#pragma unroll
    for (int i = 0; i < 8; ++i) {
      int d = vd0 + i;
      *reinterpret_cast<unsigned short*>(lbA + 4096 + ((d * 64 + vk * 2) ^ ((d & 7) << 4))) = vr[i];
    }
  }
  __syncthreads();

  f32x16 acc0 = {0.f,0.f,0.f,0.f,0.f,0.f,0.f,0.f,0.f,0.f,0.f,0.f,0.f,0.f,0.f,0.f};
  f32x16 acc1 = {0.f,0.f,0.f,0.f,0.f,0.f,0.f,0.f,0.f,0.f,0.f,0.f,0.f,0.f,0.f,0.f};
  float mrun = -1e30f, lrun = 0.f;

  for (int t = 0; t < 64; ++t) {
    char* cur = (t & 1) ? lbB : lbA;
    char* nxt = (t & 1) ? lbA : lbB;
    const bool more = (t + 1 < 64);
    u16x8 krn, vrn;
    if (more) {  // issue next-tile loads early; latency hides under compute
      int k0n = (t + 1) * 32;
      krn = *reinterpret_cast<const u16x8*>(Kp + (size_t)(k0n + krow) * D_ + kg * 8);
      vrn = *reinterpret_cast<const u16x8*>(Vp + (size_t)(k0n + vk) * D_ + vd0);
    }
    // S^T[key][q] = sum_d K[key][d] * Qs[q][d]
    f32x16 st = {0.f,0.f,0.f,0.f,0.f,0.f,0.f,0.f,0.f,0.f,0.f,0.f,0.f,0.f,0.f,0.f};
#pragma unroll
    for (int db = 0; db < 4; ++db) {
      bf16x8 kf = *reinterpret_cast<const bf16x8*>(
          cur + ((ln * 128 + db * 32 + hh * 16) ^ ((ln & 7) << 4)));
      st = __builtin_amdgcn_mfma_f32_32x32x16_bf16(kf, qf[db], st, 0, 0, 0);
    }
    // online softmax (exp2 domain; scale folded into Q)
    float tm = st[0];
#pragma unroll
    for (int r = 1; r < 16; ++r) tm = fmaxf(tm, st[r]);
    tm = fmaxf(tm, __shfl_xor(tm, 32, 64));
    if (!__all(tm <= mrun + 8.0f)) {  // defer-max (T13)
      float newm = fmaxf(mrun, tm);
      float alpha = exp2f(mrun - newm);
      mrun = newm;
      lrun *= alpha;
      acc0 *= alpha;
      acc1 *= alpha;
    }
    float p[16];
    float psum = 0.f;
#pragma unroll
    for (int r = 0; r < 16; ++r) { p[r] = exp2f(st[r] - mrun); psum += p[r]; }
    psum += __shfl_xor(psum, 32, 64);
    lrun += psum;
    // pack P to bf16 words; exchange halves so each lane gets its B-fragment
    unsigned int w0 = (unsigned)f2bf(p[0])  | ((unsigned)f2bf(p[1])  << 16);
    unsigned int w1 = (unsigned)f2bf(p[2])  | ((unsigned)f2bf(p[3])  << 16);
    unsigned int w2 = (unsigned)f2bf(p[4])  | ((unsigned)f2bf(p[5])  << 16);
    unsigned int w3 = (unsigned)f2bf(p[6])  | ((unsigned)f2bf(p[7])  << 16);
    unsigned int w4 = (unsigned)f2bf(p[8])  | ((unsigned)f2bf(p[9])  << 16);
    unsigned int w5 = (unsigned)f2bf(p[10]) | ((unsigned)f2bf(p[11]) << 16);
    unsigned int w6 = (unsigned)f2bf(p[12]) | ((unsigned)f2bf(p[13]) << 16);
    unsigned int w7 = (unsigned)f2bf(p[14]) | ((unsigned)f2bf(p[15]) << 16);
    unsigned int x0 = __shfl_xor(w0, 32, 64);
    unsigned int x1 = __shfl_xor(w1, 32, 64);
    unsigned int x2 = __shfl_xor(w2, 32, 64);
    unsigned int x3 = __shfl_xor(w3, 32, 64);
    unsigned int x4 = __shfl_xor(w4, 32, 64);
    unsigned int x5 = __shfl_xor(w5, 32, 64);
    unsigned int x6 = __shfl_xor(w6, 32, 64);
    unsigned int x7 = __shfl_xor(w7, 32, 64);
    uint4 fw0 = make_uint4(hh ? x2 : w0, hh ? x3 : w1, hh ? w2 : x0, hh ? w3 : x1);
    uint4 fw1 = make_uint4(hh ? x6 : w4, hh ? x7 : w5, hh ? w6 : x4, hh ? w7 : x5);
    bf16x8 pb0 = __builtin_bit_cast(bf16x8, fw0);
    bf16x8 pb1 = __builtin_bit_cast(bf16x8, fw1);
    // ctx^T[d][q] += sum_k Vt[d][k] * P^T[k][q]
    {
      int vd = ln;
      bf16x8 va = *reinterpret_cast<const bf16x8*>(
          cur + 4096 + ((vd * 64 + hh * 16) ^ ((vd & 7) << 4)));
      bf16x8 vb = *reinterpret_cast<const bf16x8*>(
          cur + 4096 + ((vd * 64 + 32 + hh * 16) ^ ((vd & 7) << 4)));
      acc0 = __builtin_amdgcn_mfma_f32_32x32x16_bf16(va, pb0, acc0, 0, 0, 0);
      acc0 = __builtin_amdgcn_mfma_f32_32x32x16_bf16(vb, pb1, acc0, 0, 0, 0);
    }
    {
      int vd = ln + 32;
      bf16x8 va = *reinterpret_cast<const bf16x8*>(
          cur + 4096 + ((vd * 64 + hh * 16) ^ ((vd & 7) << 4)));
      bf16x8 vb = *reinterpret_cast<const bf16x8*>(
          cur + 4096 + ((vd * 64 + 32 + hh * 16) ^ ((vd & 7) << 4)));
      acc1 = __builtin_amdgcn_mfma_f32_32x32x16_bf16(va, pb0, acc1, 0, 0, 0);
      acc1 = __builtin_amdgcn_mfma_f32_32x32x16_bf16(vb, pb1, acc1, 0, 0, 0);
    }
    if (more) {  // write the prefetched tile to the other buffer
      *reinterpret_cast<u16x8*>(nxt + kwoff) = krn;
#pragma unroll
      for (int i = 0; i < 8; ++i) {
        int d = vd0 + i;
        *reinterpret_cast<unsigned short*>(nxt + 4096 + ((d * 64 + vk * 2) ^ ((d & 7) << 4))) = vrn[i];
      }
    }
    __syncthreads();
  }

  // epilogue: ctx[b][s][e], d = (r&3) + 8*(r>>2) + 4*hh (+32 for acc1)
  float invl = 1.0f / lrun;
  float* orow = ctx + ((size_t)b * S_ + qrow) * E_ + head * D_;
#pragma unroll
  for (int g = 0; g < 4; ++g) {
    int d0 = 8 * g + 4 * hh;
    float4 o0 = make_float4(acc0[4 * g + 0] * invl, acc0[4 * g + 1] * invl,
                            acc0[4 * g + 2] * invl, acc0[4 * g + 3] * invl);
    *reinterpret_cast<float4*>(orow + d0) = o0;
    float4 o1 = make_float4(acc1[4 * g + 0] * invl, acc1[4 * g + 1] * invl,
                            acc1[4 * g + 2] * invl, acc1[4 * g + 3] * invl);
    *reinterpret_cast<float4*>(orow + d0 + 32) = o1;
  }
}

// ---------------------------------------------------------------------------
// Kernel 3: output projection (fp32). out = ctx @ W_out + b_out.
// ---------------------------------------------------------------------------
__global__ __launch_bounds__(256) void out_gemm_k(
    const float* __restrict__ Cx, const float* __restrict__ W,
    const float* __restrict__ bias, float* __restrict__ out) {
  __shared__ float As[64][17];
  __shared__ float Bs[16][64];
  const int tid = threadIdx.x;
  const int tx = tid & 15, ty = tid >> 4;
  const int n0 = blockIdx.x * 64;
  const int m0 = blockIdx.y * 64;
  const int arow = tid >> 2, acol = (tid & 3) * 4;
  const int brow = tid >> 4, bcol = (tid & 15) * 4;
  float acc[4][4] = {};
  for (int k0 = 0; k0 < E_; k0 += 16) {
    float4 av = *reinterpret_cast<const float4*>(&Cx[(size_t)(m0 + arow) * E_ + k0 + acol]);
    *reinterpret_cast<float4*>(&Bs[brow][bcol]) =
        *reinterpret_cast<const float4*>(&W[(size_t)(k0 + brow) * E_ + n0 + bcol]);
    As[arow][acol + 0] = av.x; As[arow][acol + 1] = av.y;
    As[arow][acol + 2] = av.z; As[arow][acol + 3] = av.w;
    __syncthreads();
#pragma unroll
    for (int kk = 0; kk < 16; ++kk) {
      float a0 = As[ty * 4 + 0][kk], a1 = As[ty * 4 + 1][kk];
      float a2 = As[ty * 4 + 2][kk], a3 = As[ty * 4 + 3][kk];
      float4 bv = *reinterpret_cast<const float4*>(&Bs[kk][tx * 4]);
      acc[0][0] += a0 * bv.x; acc[0][1] += a0 * bv.y; acc[0][2] += a0 * bv.z; acc[0][3] += a0 * bv.w;
      acc[1][0] += a1 * bv.x; acc[1][1] += a1 * bv.y; acc[1][2] += a1 * bv.z; acc[1][3] += a1 * bv.w;
      acc[2][0] += a2 * bv.x; acc[2][1] += a2 * bv.y; acc[2][2] += a2 * bv.z; acc[2][3] += a2 * bv.w;
      acc[3][0] += a3 * bv.x; acc[3][1] += a3 * bv.y; acc[3][2] += a3 * bv.z; acc[3][3] += a3 * bv.w;
    }
    __syncthreads();
  }
  float bl[4];
#pragma unroll
  for (int j = 0; j < 4; ++j) bl[j] = bias[n0 + tx * 4 + j];
#pragma unroll
  for (int i = 0; i < 4; ++i) {
    int mr = m0 + ty * 4 + i;
    float4 v = make_float4(acc[i][0] + bl[0], acc[i][1] + bl[1],
                           acc[i][2] + bl[2], acc[i][3] + bl[3]);
    *reinterpret_cast<float4*>(&out[(size_t)mr * E_ + n0 + tx * 4]) = v;
  }
}

extern "C" void kernel_launch(void* const* d_in, const int* in_sizes, int n_in,
                              void* d_out, int out_size, void* d_ws, size_t ws_size,
                              hipStream_t stream) {
  const float* x    = (const float*)d_in[0];
  const float* Wqkv = (const float*)d_in[1];
  const float* bqkv = (const float*)d_in[2];
  const float* Wout = (const float*)d_in[3];
  const float* bout = (const float*)d_in[4];
  float* out = (float*)d_out;

  unsigned short* qkv_ws = (unsigned short*)d_ws;  // 3*B*H*S*D bf16 = 50.3 MB
  float* ctx_ws = (float*)((char*)d_ws +
                           (size_t)3 * B_ * H_ * S_ * D_ * sizeof(unsigned short));

  qkv_gemm_k<<<dim3(N_QKV / 64, M_TOT / 64), 256, 0, stream>>>(x, Wqkv, bqkv, qkv_ws);
  attn_k<<<dim3(S_ / 128, B_ * H_), 256, 0, stream>>>(qkv_ws, ctx_ws);
  out_gemm_k<<<dim3(E_ / 64, M_TOT / 64), 256, 0, stream>>>(ctx_ws, Wout, bout, out);
}

// Round 3
// 260.941 us; speedup vs baseline: 8.7286x; 4.2331x over previous
//
#include <hip/hip_runtime.h>
#include <math.h>

#define B_ 4
#define S_ 2048
#define E_ 1024
#define H_ 16
#define D_ 64
#define M_TOT 8192
#define N_QKV 3072
#define K_ 1024

typedef __attribute__((ext_vector_type(8))) __bf16 bf16x8;
typedef __attribute__((ext_vector_type(8))) unsigned short u16x8;
typedef __attribute__((ext_vector_type(16))) float f32x16;

static __device__ __forceinline__ unsigned short f2bf(float f) {
  union { float f; unsigned int u; } x; x.f = f;
  unsigned int r = x.u + 0x7FFFu + ((x.u >> 16) & 1u);
  return (unsigned short)(r >> 16);
}
static __device__ __forceinline__ float bf2f(unsigned short u) {
  union { unsigned int u; float f; } x; x.u = ((unsigned int)u) << 16;
  return x.f;
}

static __device__ __forceinline__ void gload16(const void* g, void* l) {
  __builtin_amdgcn_global_load_lds(
      (const __attribute__((address_space(1))) void*)g,
      (__attribute__((address_space(3))) void*)l, 16, 0, 0);
}

// ---------------------------------------------------------------------------
// Converters: fp32 -> bf16 (flat), and fp32 [K][N] -> bf16 [N][K] (transpose)
// ---------------------------------------------------------------------------
__global__ __launch_bounds__(256) void cvt_k(const float* __restrict__ in,
                                             unsigned short* __restrict__ out,
                                             int n8) {
  int i = blockIdx.x * 256 + threadIdx.x;
  if (i >= n8) return;
  float4 a = *reinterpret_cast<const float4*>(in + (size_t)i * 8);
  float4 b = *reinterpret_cast<const float4*>(in + (size_t)i * 8 + 4);
  u16x8 o;
  o[0] = f2bf(a.x); o[1] = f2bf(a.y); o[2] = f2bf(a.z); o[3] = f2bf(a.w);
  o[4] = f2bf(b.x); o[5] = f2bf(b.y); o[6] = f2bf(b.z); o[7] = f2bf(b.w);
  *reinterpret_cast<u16x8*>(out + (size_t)i * 8) = o;
}

__global__ __launch_bounds__(256) void tcvt_k(const float* __restrict__ in,
                                              unsigned short* __restrict__ out,
                                              int K, int N) {
  __shared__ float t[64][65];
  int n0 = blockIdx.x * 64, k0 = blockIdx.y * 64;
  int r = threadIdx.x >> 4, c = (threadIdx.x & 15) * 4;
#pragma unroll
  for (int it = 0; it < 4; ++it) {
    float4 v = *reinterpret_cast<const float4*>(&in[(size_t)(k0 + r + it * 16) * N + n0 + c]);
    t[r + it * 16][c + 0] = v.x; t[r + it * 16][c + 1] = v.y;
    t[r + it * 16][c + 2] = v.z; t[r + it * 16][c + 3] = v.w;
  }
  __syncthreads();
#pragma unroll
  for (int it = 0; it < 4; ++it) {
    int rr = r + it * 16;
    ushort4 o;
    o.x = f2bf(t[c + 0][rr]); o.y = f2bf(t[c + 1][rr]);
    o.z = f2bf(t[c + 2][rr]); o.w = f2bf(t[c + 3][rr]);
    *reinterpret_cast<ushort4*>(&out[(size_t)(n0 + rr) * K + k0 + c]) = o;
  }
}

// ---------------------------------------------------------------------------
// bf16 MFMA GEMM: C[M][N] = A[M][K] @ BT[N][K]^T (+bias).
// Tile 128(M) x 256(N), BK=32, 4 waves each computing 128x64 (4x2 frags of
// 32x32x16). LDS double-buffered: A 128x64B + BT 256x64B = 24KB/buf, with
// 16B-slot XOR swizzle  sigma(r) = ((r>>1)&3)<<4  applied on the READ side
// and pre-applied to the per-lane GLOBAL source so the linear lane-order
// write of global_load_lds lands swizzled (conflict-free ds_read_b128).
// MODE 0: scatter-store bf16 into qkv [3][B][H][S][D].  MODE 1: fp32 C+bias.
// ---------------------------------------------------------------------------
template <int MODE>
__global__ __launch_bounds__(256) void gemm_k(
    const unsigned short* __restrict__ A, const unsigned short* __restrict__ BT,
    const float* __restrict__ bias, void* __restrict__ Cout) {
  __shared__ __attribute__((aligned(128))) char lds[2][24576];
  const int tid = threadIdx.x;
  const int wv = tid >> 6, lane = tid & 63;
  const int ln = lane & 31, hh = lane >> 5;
  const int m0 = blockIdx.y * 128, n0 = blockIdx.x * 256;
  const int r4 = lane >> 2, slot = lane & 3;

  const char* Ab = (const char*)A;
  const char* Bb = (const char*)BT;
  size_t a_off[2], b_off[4];
#pragma unroll
  for (int i = 0; i < 2; ++i) {
    int r = wv * 32 + i * 16 + r4;
    a_off[i] = (size_t)(m0 + r) * (K_ * 2) + (size_t)((slot ^ ((r >> 1) & 3)) * 16);
  }
#pragma unroll
  for (int j = 0; j < 4; ++j) {
    int r = wv * 64 + j * 16 + r4;
    b_off[j] = (size_t)(n0 + r) * (K_ * 2) + (size_t)((slot ^ ((r >> 1) & 3)) * 16);
  }

  f32x16 acc[4][2];
#pragma unroll
  for (int gr = 0; gr < 4; ++gr)
#pragma unroll
    for (int gc = 0; gc < 2; ++gc)
#pragma unroll
      for (int e = 0; e < 16; ++e) acc[gr][gc][e] = 0.f;

#define STAGE(dst, tt)                                                        \
  do {                                                                        \
    char* _d = (dst);                                                         \
    size_t _ko = (size_t)(tt) * 64;                                           \
    _Pragma("unroll") for (int i = 0; i < 2; ++i)                             \
        gload16(Ab + a_off[i] + _ko, _d + (wv * 32 + i * 16) * 64);           \
    _Pragma("unroll") for (int j = 0; j < 4; ++j)                             \
        gload16(Bb + b_off[j] + _ko, _d + 8192 + (wv * 64 + j * 16) * 64);    \
  } while (0)

  STAGE(&lds[0][0], 0);
  __syncthreads();
  for (int t = 0; t < K_ / 32; ++t) {
    char* cur = &lds[t & 1][0];
    char* nxt = &lds[(t + 1) & 1][0];
    if (t + 1 < K_ / 32) STAGE(nxt, t + 1);
#pragma unroll
    for (int s = 0; s < 2; ++s) {
      const int cb = s * 32 + hh * 16;
      bf16x8 af[4], bfr[2];
#pragma unroll
      for (int gr = 0; gr < 4; ++gr) {
        int row = gr * 32 + ln;
        af[gr] = *reinterpret_cast<const bf16x8*>(
            cur + row * 64 + (cb ^ (((row >> 1) & 3) << 4)));
      }
#pragma unroll
      for (int gc = 0; gc < 2; ++gc) {
        int row = wv * 64 + gc * 32 + ln;
        bfr[gc] = *reinterpret_cast<const bf16x8*>(
            cur + 8192 + row * 64 + (cb ^ (((row >> 1) & 3) << 4)));
      }
#pragma unroll
      for (int gr = 0; gr < 4; ++gr)
#pragma unroll
        for (int gc = 0; gc < 2; ++gc)
          acc[gr][gc] = __builtin_amdgcn_mfma_f32_32x32x16_bf16(
              af[gr], bfr[gc], acc[gr][gc], 0, 0, 0);
    }
    __syncthreads();
  }
#undef STAGE

  // epilogue. C row = m0 + gr*32 + 4*hh + (r&3) + 8*(r>>2); col = n0+wv*64+gc*32+ln
  const int ncol0 = n0 + wv * 64;
  if (MODE == 0) {
    unsigned short* qkv = (unsigned short*)Cout;
#pragma unroll
    for (int gc = 0; gc < 2; ++gc) {
      int n = ncol0 + gc * 32 + ln;
      float bv = bias[n];
      int which = n >> 10, h = (n >> 6) & 15, d = n & 63;
      unsigned short* base =
          qkv + (((size_t)which * B_ * H_ + h) * S_) * D_ + d;  // + bi*H_*S_*D_ + si*D_
#pragma unroll
      for (int gr = 0; gr < 4; ++gr)
#pragma unroll
        for (int r = 0; r < 16; ++r) {
          int m = m0 + gr * 32 + 4 * hh + (r & 3) + 8 * (r >> 2);
          int bi = m >> 11, si = m & 2047;
          base[((size_t)bi * H_ * S_ + si) * D_] = f2bf(acc[gr][gc][r] + bv);
          base += 0;  // keep simple; compiler folds
        }
    }
  } else {
    float* out = (float*)Cout;
#pragma unroll
    for (int gc = 0; gc < 2; ++gc) {
      int n = ncol0 + gc * 32 + ln;
      float bv = bias[n];
#pragma unroll
      for (int gr = 0; gr < 4; ++gr)
#pragma unroll
        for (int r = 0; r < 16; ++r) {
          int m = m0 + gr * 32 + 4 * hh + (r & 3) + 8 * (r >> 2);
          out[(size_t)m * E_ + n] = acc[gr][gc][r] + bv;
        }
    }
  }
}

// ---------------------------------------------------------------------------
// bf16 MFMA flash attention (unchanged from R2 except ctx stored as bf16).
// ---------------------------------------------------------------------------
__global__ __launch_bounds__(256, 4) void attn_k(
    const unsigned short* __restrict__ qkv, unsigned short* __restrict__ ctx) {
  __shared__ unsigned short lds[2][4096];
  const int tid = threadIdx.x;
  const int wv = tid >> 6;
  const int lane = tid & 63;
  const int ln = lane & 31;
  const int hh = lane >> 5;
  const int q0 = blockIdx.x * 128;
  const int bh = blockIdx.y;
  const int b = bh >> 4, head = bh & 15;
  const size_t SZ = (size_t)B_ * H_ * S_ * D_;
  const size_t plane = ((size_t)b * H_ + head) * (size_t)S_ * D_;
  const unsigned short* Qp = qkv + plane;
  const unsigned short* Kp = qkv + SZ + plane;
  const unsigned short* Vp = qkv + 2 * SZ + plane;

  const float SC = 0.125f * 1.4426950408889634f;
  const int qrow = q0 + wv * 32 + ln;
  bf16x8 qf[4];
#pragma unroll
  for (int db = 0; db < 4; ++db) {
    u16x8 qr = *reinterpret_cast<const u16x8*>(Qp + (size_t)qrow * D_ + db * 16 + hh * 8);
    u16x8 qs;
#pragma unroll
    for (int j = 0; j < 8; ++j) qs[j] = f2bf(bf2f(qr[j]) * SC);
    qf[db] = __builtin_bit_cast(bf16x8, qs);
  }

  const int krow = tid >> 3, kg = tid & 7;
  const int vk = tid & 31, vd0 = (tid >> 5) * 8;
  const int kwoff = (krow * 128 + kg * 16) ^ ((krow & 7) << 4);
  char* lbA = (char*)&lds[0][0];
  char* lbB = (char*)&lds[1][0];

  {
    u16x8 kr = *reinterpret_cast<const u16x8*>(Kp + (size_t)krow * D_ + kg * 8);
    u16x8 vr = *reinterpret_cast<const u16x8*>(Vp + (size_t)vk * D_ + vd0);
    *reinterpret_cast<u16x8*>(lbA + kwoff) = kr;
#pragma unroll
    for (int i = 0; i < 8; ++i) {
      int d = vd0 + i;
      *reinterpret_cast<unsigned short*>(lbA + 4096 + ((d * 64 + vk * 2) ^ ((d & 7) << 4))) = vr[i];
    }
  }
  __syncthreads();

  f32x16 acc0, acc1;
#pragma unroll
  for (int e = 0; e < 16; ++e) { acc0[e] = 0.f; acc1[e] = 0.f; }
  float mrun = -1e30f, lrun = 0.f;

  for (int t = 0; t < 64; ++t) {
    char* cur = (t & 1) ? lbB : lbA;
    char* nxt = (t & 1) ? lbA : lbB;
    const bool more = (t + 1 < 64);
    u16x8 krn, vrn;
    if (more) {
      int k0n = (t + 1) * 32;
      krn = *reinterpret_cast<const u16x8*>(Kp + (size_t)(k0n + krow) * D_ + kg * 8);
      vrn = *reinterpret_cast<const u16x8*>(Vp + (size_t)(k0n + vk) * D_ + vd0);
    }
    f32x16 st;
#pragma unroll
    for (int e = 0; e < 16; ++e) st[e] = 0.f;
#pragma unroll
    for (int db = 0; db < 4; ++db) {
      bf16x8 kf = *reinterpret_cast<const bf16x8*>(
          cur + ((ln * 128 + db * 32 + hh * 16) ^ ((ln & 7) << 4)));
      st = __builtin_amdgcn_mfma_f32_32x32x16_bf16(kf, qf[db], st, 0, 0, 0);
    }
    float tm = st[0];
#pragma unroll
    for (int r = 1; r < 16; ++r) tm = fmaxf(tm, st[r]);
    tm = fmaxf(tm, __shfl_xor(tm, 32, 64));
    if (!__all(tm <= mrun + 8.0f)) {
      float newm = fmaxf(mrun, tm);
      float alpha = exp2f(mrun - newm);
      mrun = newm;
      lrun *= alpha;
      acc0 *= alpha;
      acc1 *= alpha;
    }
    float p[16];
    float psum = 0.f;
#pragma unroll
    for (int r = 0; r < 16; ++r) { p[r] = exp2f(st[r] - mrun); psum += p[r]; }
    psum += __shfl_xor(psum, 32, 64);
    lrun += psum;
    unsigned int w0 = (unsigned)f2bf(p[0])  | ((unsigned)f2bf(p[1])  << 16);
    unsigned int w1 = (unsigned)f2bf(p[2])  | ((unsigned)f2bf(p[3])  << 16);
    unsigned int w2 = (unsigned)f2bf(p[4])  | ((unsigned)f2bf(p[5])  << 16);
    unsigned int w3 = (unsigned)f2bf(p[6])  | ((unsigned)f2bf(p[7])  << 16);
    unsigned int w4 = (unsigned)f2bf(p[8])  | ((unsigned)f2bf(p[9])  << 16);
    unsigned int w5 = (unsigned)f2bf(p[10]) | ((unsigned)f2bf(p[11]) << 16);
    unsigned int w6 = (unsigned)f2bf(p[12]) | ((unsigned)f2bf(p[13]) << 16);
    unsigned int w7 = (unsigned)f2bf(p[14]) | ((unsigned)f2bf(p[15]) << 16);
    unsigned int x0 = __shfl_xor(w0, 32, 64);
    unsigned int x1 = __shfl_xor(w1, 32, 64);
    unsigned int x2 = __shfl_xor(w2, 32, 64);
    unsigned int x3 = __shfl_xor(w3, 32, 64);
    unsigned int x4 = __shfl_xor(w4, 32, 64);
    unsigned int x5 = __shfl_xor(w5, 32, 64);
    unsigned int x6 = __shfl_xor(w6, 32, 64);
    unsigned int x7 = __shfl_xor(w7, 32, 64);
    uint4 fw0 = make_uint4(hh ? x2 : w0, hh ? x3 : w1, hh ? w2 : x0, hh ? w3 : x1);
    uint4 fw1 = make_uint4(hh ? x6 : w4, hh ? x7 : w5, hh ? w6 : x4, hh ? w7 : x5);
    bf16x8 pb0 = __builtin_bit_cast(bf16x8, fw0);
    bf16x8 pb1 = __builtin_bit_cast(bf16x8, fw1);
    {
      int vd = ln;
      bf16x8 va = *reinterpret_cast<const bf16x8*>(
          cur + 4096 + ((vd * 64 + hh * 16) ^ ((vd & 7) << 4)));
      bf16x8 vb = *reinterpret_cast<const bf16x8*>(
          cur + 4096 + ((vd * 64 + 32 + hh * 16) ^ ((vd & 7) << 4)));
      acc0 = __builtin_amdgcn_mfma_f32_32x32x16_bf16(va, pb0, acc0, 0, 0, 0);
      acc0 = __builtin_amdgcn_mfma_f32_32x32x16_bf16(vb, pb1, acc0, 0, 0, 0);
    }
    {
      int vd = ln + 32;
      bf16x8 va = *reinterpret_cast<const bf16x8*>(
          cur + 4096 + ((vd * 64 + hh * 16) ^ ((vd & 7) << 4)));
      bf16x8 vb = *reinterpret_cast<const bf16x8*>(
          cur + 4096 + ((vd * 64 + 32 + hh * 16) ^ ((vd & 7) << 4)));
      acc1 = __builtin_amdgcn_mfma_f32_32x32x16_bf16(va, pb0, acc1, 0, 0, 0);
      acc1 = __builtin_amdgcn_mfma_f32_32x32x16_bf16(vb, pb1, acc1, 0, 0, 0);
    }
    if (more) {
      *reinterpret_cast<u16x8*>(nxt + kwoff) = krn;
#pragma unroll
      for (int i = 0; i < 8; ++i) {
        int d = vd0 + i;
        *reinterpret_cast<unsigned short*>(nxt + 4096 + ((d * 64 + vk * 2) ^ ((d & 7) << 4))) = vrn[i];
      }
    }
    __syncthreads();
  }

  float invl = 1.0f / lrun;
  unsigned short* orow = ctx + ((size_t)b * S_ + qrow) * E_ + head * D_;
#pragma unroll
  for (int g = 0; g < 4; ++g) {
    int d0 = 8 * g + 4 * hh;
    ushort4 o0, o1;
    o0.x = f2bf(acc0[4 * g + 0] * invl); o0.y = f2bf(acc0[4 * g + 1] * invl);
    o0.z = f2bf(acc0[4 * g + 2] * invl); o0.w = f2bf(acc0[4 * g + 3] * invl);
    o1.x = f2bf(acc1[4 * g + 0] * invl); o1.y = f2bf(acc1[4 * g + 1] * invl);
    o1.z = f2bf(acc1[4 * g + 2] * invl); o1.w = f2bf(acc1[4 * g + 3] * invl);
    *reinterpret_cast<ushort4*>(orow + d0) = o0;
    *reinterpret_cast<ushort4*>(orow + d0 + 32) = o1;
  }
}

extern "C" void kernel_launch(void* const* d_in, const int* in_sizes, int n_in,
                              void* d_out, int out_size, void* d_ws, size_t ws_size,
                              hipStream_t stream) {
  const float* x    = (const float*)d_in[0];
  const float* Wqkv = (const float*)d_in[1];
  const float* bqkv = (const float*)d_in[2];
  const float* Wout = (const float*)d_in[3];
  const float* bout = (const float*)d_in[4];
  float* out = (float*)d_out;

  char* ws = (char*)d_ws;
  unsigned short* qkv_b = (unsigned short*)ws;                     ws += (size_t)3 * B_ * H_ * S_ * D_ * 2;  // 50.3 MB
  unsigned short* ctx_b = (unsigned short*)ws;                     ws += (size_t)M_TOT * E_ * 2;             // 16.8 MB
  unsigned short* xb    = (unsigned short*)ws;                     ws += (size_t)M_TOT * E_ * 2;             // 16.8 MB
  unsigned short* wqT   = (unsigned short*)ws;                     ws += (size_t)N_QKV * K_ * 2;             //  6.3 MB
  unsigned short* woT   = (unsigned short*)ws;                                                               //  2.1 MB

  cvt_k<<<dim3(M_TOT * E_ / 8 / 256), 256, 0, stream>>>(x, xb, M_TOT * E_ / 8);
  tcvt_k<<<dim3(N_QKV / 64, K_ / 64), 256, 0, stream>>>(Wqkv, wqT, K_, N_QKV);
  tcvt_k<<<dim3(E_ / 64, K_ / 64), 256, 0, stream>>>(Wout, woT, K_, E_);

  gemm_k<0><<<dim3(N_QKV / 256, M_TOT / 128), 256, 0, stream>>>(xb, wqT, bqkv, qkv_b);
  attn_k<<<dim3(S_ / 128, B_ * H_), 256, 0, stream>>>(qkv_b, ctx_b);
  gemm_k<1><<<dim3(E_ / 256, M_TOT / 128), 256, 0, stream>>>(ctx_b, woT, bout, out);
}

// Round 4
// 238.889 us; speedup vs baseline: 9.5344x; 1.0923x over previous
//
#include <hip/hip_runtime.h>
#include <math.h>

#define B_ 4
#define S_ 2048
#define E_ 1024
#define H_ 16
#define D_ 64
#define M_TOT 8192
#define N_QKV 3072
#define K_ 1024

typedef __attribute__((ext_vector_type(8))) __bf16 bf16x8;
typedef __attribute__((ext_vector_type(2))) __bf16 bf16x2;
typedef __attribute__((ext_vector_type(8))) unsigned short u16x8;
typedef __attribute__((ext_vector_type(16))) float f32x16;

static __device__ __forceinline__ float bf2f(unsigned short u) {
  union { unsigned int u; float f; } x; x.u = ((unsigned int)u) << 16;
  return x.f;
}
// RNE f32->bf16 pair packed into one u32 (compiler emits v_cvt_pk_bf16_f32)
static __device__ __forceinline__ unsigned int pack_bf16(float lo, float hi) {
  bf16x2 t; t[0] = (__bf16)lo; t[1] = (__bf16)hi;
  return __builtin_bit_cast(unsigned int, t);
}
// v_permlane32_swap_b32: a.hi <-> b.lo  =>  a'={a.lo,b.lo}, b'={a.hi,b.hi}
static __device__ __forceinline__ void perm32swap(unsigned int& a, unsigned int& b) {
  asm volatile("v_permlane32_swap_b32 %0, %1" : "+v"(a), "+v"(b));
}

static __device__ __forceinline__ void gload16(const void* g, void* l) {
  __builtin_amdgcn_global_load_lds(
      (const __attribute__((address_space(1))) void*)g,
      (__attribute__((address_space(3))) void*)l, 16, 0, 0);
}

// ---------------------------------------------------------------------------
// Converters: fp32 -> bf16 (flat), and fp32 [K][N] -> bf16 [N][K] (transpose)
// ---------------------------------------------------------------------------
__global__ __launch_bounds__(256) void cvt_k(const float* __restrict__ in,
                                             unsigned short* __restrict__ out,
                                             int n8) {
  int i = blockIdx.x * 256 + threadIdx.x;
  if (i >= n8) return;
  float4 a = *reinterpret_cast<const float4*>(in + (size_t)i * 8);
  float4 b = *reinterpret_cast<const float4*>(in + (size_t)i * 8 + 4);
  uint4 o;
  o.x = pack_bf16(a.x, a.y); o.y = pack_bf16(a.z, a.w);
  o.z = pack_bf16(b.x, b.y); o.w = pack_bf16(b.z, b.w);
  *reinterpret_cast<uint4*>(out + (size_t)i * 8) = o;
}

__global__ __launch_bounds__(256) void tcvt_k(const float* __restrict__ in,
                                              unsigned short* __restrict__ out,
                                              int K, int N) {
  __shared__ float t[64][65];
  int n0 = blockIdx.x * 64, k0 = blockIdx.y * 64;
  int r = threadIdx.x >> 4, c = (threadIdx.x & 15) * 4;
#pragma unroll
  for (int it = 0; it < 4; ++it) {
    float4 v = *reinterpret_cast<const float4*>(&in[(size_t)(k0 + r + it * 16) * N + n0 + c]);
    t[r + it * 16][c + 0] = v.x; t[r + it * 16][c + 1] = v.y;
    t[r + it * 16][c + 2] = v.z; t[r + it * 16][c + 3] = v.w;
  }
  __syncthreads();
#pragma unroll
  for (int it = 0; it < 4; ++it) {
    int rr = r + it * 16;
    uint2 o;
    o.x = pack_bf16(t[c + 0][rr], t[c + 1][rr]);
    o.y = pack_bf16(t[c + 2][rr], t[c + 3][rr]);
    *reinterpret_cast<uint2*>(&out[(size_t)(n0 + rr) * K + k0 + c]) = o;
  }
}

// ---------------------------------------------------------------------------
// bf16 MFMA GEMM: C[M][N] = A[M][K] @ BT[N][K]^T (+bias).
// Tile 128(M) x 256(N), BK=32, 4 waves each computing 128x64 (4x2 frags of
// 32x32x16). LDS double-buffered; 16B-slot XOR swizzle on read side,
// pre-applied to per-lane global source for global_load_lds.
// MODE 0: scatter-store bf16 into qkv [3][B][H][S][D].  MODE 1: fp32 C+bias.
// ---------------------------------------------------------------------------
template <int MODE>
__global__ __launch_bounds__(256) void gemm_k(
    const unsigned short* __restrict__ A, const unsigned short* __restrict__ BT,
    const float* __restrict__ bias, void* __restrict__ Cout) {
  __shared__ __attribute__((aligned(128))) char lds[2][24576];
  const int tid = threadIdx.x;
  const int wv = tid >> 6, lane = tid & 63;
  const int ln = lane & 31, hh = lane >> 5;
  const int m0 = blockIdx.y * 128, n0 = blockIdx.x * 256;
  const int r4 = lane >> 2, slot = lane & 3;

  const char* Ab = (const char*)A;
  const char* Bb = (const char*)BT;
  size_t a_off[2], b_off[4];
#pragma unroll
  for (int i = 0; i < 2; ++i) {
    int r = wv * 32 + i * 16 + r4;
    a_off[i] = (size_t)(m0 + r) * (K_ * 2) + (size_t)((slot ^ ((r >> 1) & 3)) * 16);
  }
#pragma unroll
  for (int j = 0; j < 4; ++j) {
    int r = wv * 64 + j * 16 + r4;
    b_off[j] = (size_t)(n0 + r) * (K_ * 2) + (size_t)((slot ^ ((r >> 1) & 3)) * 16);
  }

  f32x16 acc[4][2];
#pragma unroll
  for (int gr = 0; gr < 4; ++gr)
#pragma unroll
    for (int gc = 0; gc < 2; ++gc)
#pragma unroll
      for (int e = 0; e < 16; ++e) acc[gr][gc][e] = 0.f;

#define STAGE(dst, tt)                                                        \
  do {                                                                        \
    char* _d = (dst);                                                         \
    size_t _ko = (size_t)(tt) * 64;                                           \
    _Pragma("unroll") for (int i = 0; i < 2; ++i)                             \
        gload16(Ab + a_off[i] + _ko, _d + (wv * 32 + i * 16) * 64);           \
    _Pragma("unroll") for (int j = 0; j < 4; ++j)                             \
        gload16(Bb + b_off[j] + _ko, _d + 8192 + (wv * 64 + j * 16) * 64);    \
  } while (0)

  STAGE(&lds[0][0], 0);
  __syncthreads();
  for (int t = 0; t < K_ / 32; ++t) {
    char* cur = &lds[t & 1][0];
    char* nxt = &lds[(t + 1) & 1][0];
    if (t + 1 < K_ / 32) STAGE(nxt, t + 1);
#pragma unroll
    for (int s = 0; s < 2; ++s) {
      const int cb = s * 32 + hh * 16;
      bf16x8 af[4], bfr[2];
#pragma unroll
      for (int gr = 0; gr < 4; ++gr) {
        int row = gr * 32 + ln;
        af[gr] = *reinterpret_cast<const bf16x8*>(
            cur + row * 64 + (cb ^ (((row >> 1) & 3) << 4)));
      }
#pragma unroll
      for (int gc = 0; gc < 2; ++gc) {
        int row = wv * 64 + gc * 32 + ln;
        bfr[gc] = *reinterpret_cast<const bf16x8*>(
            cur + 8192 + row * 64 + (cb ^ (((row >> 1) & 3) << 4)));
      }
#pragma unroll
      for (int gr = 0; gr < 4; ++gr)
#pragma unroll
        for (int gc = 0; gc < 2; ++gc)
          acc[gr][gc] = __builtin_amdgcn_mfma_f32_32x32x16_bf16(
              af[gr], bfr[gc], acc[gr][gc], 0, 0, 0);
    }
    __syncthreads();
  }
#undef STAGE

  // epilogue. C row = m0 + gr*32 + 4*hh + (r&3) + 8*(r>>2); col = n0+wv*64+gc*32+ln
  const int ncol0 = n0 + wv * 64;
  if (MODE == 0) {
    unsigned short* qkv = (unsigned short*)Cout;
#pragma unroll
    for (int gc = 0; gc < 2; ++gc) {
      int n = ncol0 + gc * 32 + ln;
      float bv = bias[n];
      int which = n >> 10, h = (n >> 6) & 15, d = n & 63;
      unsigned short* base =
          qkv + (((size_t)which * B_ * H_ + h) * S_) * D_ + d;
#pragma unroll
      for (int gr = 0; gr < 4; ++gr)
#pragma unroll
        for (int r = 0; r < 16; r += 2) {  // rows m, m+1 share a cvt_pk
          int m = m0 + gr * 32 + 4 * hh + (r & 3) + 8 * (r >> 2);
          unsigned int w = pack_bf16(acc[gr][gc][r] + bv, acc[gr][gc][r + 1] + bv);
          int bi = m >> 11, si = m & 2047;
          size_t off = ((size_t)bi * H_ * S_ + si) * D_;
          base[off] = (unsigned short)w;
          base[off + D_] = (unsigned short)(w >> 16);
        }
    }
  } else {
    float* out = (float*)Cout;
#pragma unroll
    for (int gc = 0; gc < 2; ++gc) {
      int n = ncol0 + gc * 32 + ln;
      float bv = bias[n];
#pragma unroll
      for (int gr = 0; gr < 4; ++gr)
#pragma unroll
        for (int r = 0; r < 16; ++r) {
          int m = m0 + gr * 32 + 4 * hh + (r & 3) + 8 * (r >> 2);
          out[(size_t)m * E_ + n] = acc[gr][gc][r] + bv;
        }
    }
  }
}

// ---------------------------------------------------------------------------
// bf16 MFMA flash attention, swapped QK^T. VALU diet vs R3: native-cast
// cvt_pk packing (T12), permlane32_swap half-exchange (replaces 8 shfl_xor
// + 8 cndmask), max3-friendly reduction trees.
// ---------------------------------------------------------------------------
__global__ __launch_bounds__(256, 4) void attn_k(
    const unsigned short* __restrict__ qkv, unsigned short* __restrict__ ctx) {
  __shared__ unsigned short lds[2][4096];
  const int tid = threadIdx.x;
  const int wv = tid >> 6;
  const int lane = tid & 63;
  const int ln = lane & 31;
  const int hh = lane >> 5;
  const int q0 = blockIdx.x * 128;
  const int bh = blockIdx.y;
  const int b = bh >> 4, head = bh & 15;
  const size_t SZ = (size_t)B_ * H_ * S_ * D_;
  const size_t plane = ((size_t)b * H_ + head) * (size_t)S_ * D_;
  const unsigned short* Qp = qkv + plane;
  const unsigned short* Kp = qkv + SZ + plane;
  const unsigned short* Vp = qkv + 2 * SZ + plane;

  const float SC = 0.125f * 1.4426950408889634f;
  const int qrow = q0 + wv * 32 + ln;
  bf16x8 qf[4];
#pragma unroll
  for (int db = 0; db < 4; ++db) {
    u16x8 qr = *reinterpret_cast<const u16x8*>(Qp + (size_t)qrow * D_ + db * 16 + hh * 8);
    bf16x8 qs;
#pragma unroll
    for (int j = 0; j < 8; ++j) qs[j] = (__bf16)(bf2f(qr[j]) * SC);
    qf[db] = qs;
  }

  const int krow = tid >> 3, kg = tid & 7;
  const int vk = tid & 31, vd0 = (tid >> 5) * 8;
  const int kwoff = (krow * 128 + kg * 16) ^ ((krow & 7) << 4);
  char* lbA = (char*)&lds[0][0];
  char* lbB = (char*)&lds[1][0];

  {
    u16x8 kr = *reinterpret_cast<const u16x8*>(Kp + (size_t)krow * D_ + kg * 8);
    u16x8 vr = *reinterpret_cast<const u16x8*>(Vp + (size_t)vk * D_ + vd0);
    *reinterpret_cast<u16x8*>(lbA + kwoff) = kr;
#pragma unroll
    for (int i = 0; i < 8; ++i) {
      int d = vd0 + i;
      *reinterpret_cast<unsigned short*>(lbA + 4096 + ((d * 64 + vk * 2) ^ ((d & 7) << 4))) = vr[i];
    }
  }
  __syncthreads();

  f32x16 acc0, acc1;
#pragma unroll
  for (int e = 0; e < 16; ++e) { acc0[e] = 0.f; acc1[e] = 0.f; }
  float mrun = -1e30f, lrun = 0.f;

  for (int t = 0; t < 64; ++t) {
    char* cur = (t & 1) ? lbB : lbA;
    char* nxt = (t & 1) ? lbA : lbB;
    const bool more = (t + 1 < 64);
    u16x8 krn, vrn;
    if (more) {
      int k0n = (t + 1) * 32;
      krn = *reinterpret_cast<const u16x8*>(Kp + (size_t)(k0n + krow) * D_ + kg * 8);
      vrn = *reinterpret_cast<const u16x8*>(Vp + (size_t)(k0n + vk) * D_ + vd0);
    }
    f32x16 st;
#pragma unroll
    for (int e = 0; e < 16; ++e) st[e] = 0.f;
#pragma unroll
    for (int db = 0; db < 4; ++db) {
      bf16x8 kf = *reinterpret_cast<const bf16x8*>(
          cur + ((ln * 128 + db * 32 + hh * 16) ^ ((ln & 7) << 4)));
      st = __builtin_amdgcn_mfma_f32_32x32x16_bf16(kf, qf[db], st, 0, 0, 0);
    }
    // max via max3-foldable tree
    float ta = fmaxf(fmaxf(st[0], st[1]), st[2]);
    float tb = fmaxf(fmaxf(st[3], st[4]), st[5]);
    float tc = fmaxf(fmaxf(st[6], st[7]), st[8]);
    float td = fmaxf(fmaxf(st[9], st[10]), st[11]);
    float te = fmaxf(fmaxf(st[12], st[13]), st[14]);
    float tm = fmaxf(fmaxf(fmaxf(ta, tb), fmaxf(tc, td)), fmaxf(te, st[15]));
    tm = fmaxf(tm, __shfl_xor(tm, 32, 64));
    if (!__all(tm <= mrun + 8.0f)) {  // defer-max (T13)
      float newm = fmaxf(mrun, tm);
      float alpha = exp2f(mrun - newm);
      mrun = newm;
      lrun *= alpha;
      acc0 *= alpha;
      acc1 *= alpha;
    }
    float p[16];
#pragma unroll
    for (int r = 0; r < 16; ++r) p[r] = exp2f(st[r] - mrun);
    float s0 = (p[0] + p[1]) + (p[2] + p[3]);
    float s1 = (p[4] + p[5]) + (p[6] + p[7]);
    float s2 = (p[8] + p[9]) + (p[10] + p[11]);
    float s3 = (p[12] + p[13]) + (p[14] + p[15]);
    float psum = (s0 + s1) + (s2 + s3);
    psum += __shfl_xor(psum, 32, 64);
    lrun += psum;
    // pack P pairs -> bf16 words (v_cvt_pk_bf16_f32), then permlane half-swap
    unsigned int w0 = pack_bf16(p[0], p[1]);
    unsigned int w1 = pack_bf16(p[2], p[3]);
    unsigned int w2 = pack_bf16(p[4], p[5]);
    unsigned int w3 = pack_bf16(p[6], p[7]);
    unsigned int w4 = pack_bf16(p[8], p[9]);
    unsigned int w5 = pack_bf16(p[10], p[11]);
    unsigned int w6 = pack_bf16(p[12], p[13]);
    unsigned int w7 = pack_bf16(p[14], p[15]);
    perm32swap(w0, w2);  // w0={lo.w0,hi->lo.w2}, w2={hi.w0,own w2} (by halves)
    perm32swap(w1, w3);
    perm32swap(w4, w6);
    perm32swap(w5, w7);
    uint4 fw0 = make_uint4(w0, w1, w2, w3);
    uint4 fw1 = make_uint4(w4, w5, w6, w7);
    bf16x8 pb0 = __builtin_bit_cast(bf16x8, fw0);
    bf16x8 pb1 = __builtin_bit_cast(bf16x8, fw1);
    // ctx^T[d][q] += sum_k Vt[d][k] * P^T[k][q]
    {
      int vd = ln;
      bf16x8 va = *reinterpret_cast<const bf16x8*>(
          cur + 4096 + ((vd * 64 + hh * 16) ^ ((vd & 7) << 4)));
      bf16x8 vb = *reinterpret_cast<const bf16x8*>(
          cur + 4096 + ((vd * 64 + 32 + hh * 16) ^ ((vd & 7) << 4)));
      acc0 = __builtin_amdgcn_mfma_f32_32x32x16_bf16(va, pb0, acc0, 0, 0, 0);
      acc0 = __builtin_amdgcn_mfma_f32_32x32x16_bf16(vb, pb1, acc0, 0, 0, 0);
    }
    {
      int vd = ln + 32;
      bf16x8 va = *reinterpret_cast<const bf16x8*>(
          cur + 4096 + ((vd * 64 + hh * 16) ^ ((vd & 7) << 4)));
      bf16x8 vb = *reinterpret_cast<const bf16x8*>(
          cur + 4096 + ((vd * 64 + 32 + hh * 16) ^ ((vd & 7) << 4)));
      acc1 = __builtin_amdgcn_mfma_f32_32x32x16_bf16(va, pb0, acc1, 0, 0, 0);
      acc1 = __builtin_amdgcn_mfma_f32_32x32x16_bf16(vb, pb1, acc1, 0, 0, 0);
    }
    if (more) {
      *reinterpret_cast<u16x8*>(nxt + kwoff) = krn;
#pragma unroll
      for (int i = 0; i < 8; ++i) {
        int d = vd0 + i;
        *reinterpret_cast<unsigned short*>(nxt + 4096 + ((d * 64 + vk * 2) ^ ((d & 7) << 4))) = vrn[i];
      }
    }
    __syncthreads();
  }

  float invl = 1.0f / lrun;
  unsigned short* orow = ctx + ((size_t)b * S_ + qrow) * E_ + head * D_;
#pragma unroll
  for (int g = 0; g < 4; ++g) {
    int d0 = 8 * g + 4 * hh;
    uint2 o0, o1;
    o0.x = pack_bf16(acc0[4 * g + 0] * invl, acc0[4 * g + 1] * invl);
    o0.y = pack_bf16(acc0[4 * g + 2] * invl, acc0[4 * g + 3] * invl);
    o1.x = pack_bf16(acc1[4 * g + 0] * invl, acc1[4 * g + 1] * invl);
    o1.y = pack_bf16(acc1[4 * g + 2] * invl, acc1[4 * g + 3] * invl);
    *reinterpret_cast<uint2*>(orow + d0) = o0;
    *reinterpret_cast<uint2*>(orow + d0 + 32) = o1;
  }
}

extern "C" void kernel_launch(void* const* d_in, const int* in_sizes, int n_in,
                              void* d_out, int out_size, void* d_ws, size_t ws_size,
                              hipStream_t stream) {
  const float* x    = (const float*)d_in[0];
  const float* Wqkv = (const float*)d_in[1];
  const float* bqkv = (const float*)d_in[2];
  const float* Wout = (const float*)d_in[3];
  const float* bout = (const float*)d_in[4];
  float* out = (float*)d_out;

  char* ws = (char*)d_ws;
  unsigned short* qkv_b = (unsigned short*)ws;                     ws += (size_t)3 * B_ * H_ * S_ * D_ * 2;
  unsigned short* ctx_b = (unsigned short*)ws;                     ws += (size_t)M_TOT * E_ * 2;
  unsigned short* xb    = (unsigned short*)ws;                     ws += (size_t)M_TOT * E_ * 2;
  unsigned short* wqT   = (unsigned short*)ws;                     ws += (size_t)N_QKV * K_ * 2;
  unsigned short* woT   = (unsigned short*)ws;

  cvt_k<<<dim3(M_TOT * E_ / 8 / 256), 256, 0, stream>>>(x, xb, M_TOT * E_ / 8);
  tcvt_k<<<dim3(N_QKV / 64, K_ / 64), 256, 0, stream>>>(Wqkv, wqT, K_, N_QKV);
  tcvt_k<<<dim3(E_ / 64, K_ / 64), 256, 0, stream>>>(Wout, woT, K_, E_);

  gemm_k<0><<<dim3(N_QKV / 256, M_TOT / 128), 256, 0, stream>>>(xb, wqT, bqkv, qkv_b);
  attn_k<<<dim3(S_ / 128, B_ * H_), 256, 0, stream>>>(qkv_b, ctx_b);
  gemm_k<1><<<dim3(E_ / 256, M_TOT / 128), 256, 0, stream>>>(ctx_b, woT, bout, out);
}